// Round 1
// baseline (909.820 us; speedup 1.0000x reference)
//
#include <hip/hip_runtime.h>
#include <hip/hip_bf16.h>

#define NNODES 30000
#define NEDGES 480000
#define DIM 256
#define NHEAD 8
#define CHAN 32
#define HC 256
#define NEG_SLOPE 0.2f
#define SCAN_CHUNK 1024
#define NCHUNK 30   // ceil(30000/1024)

// ---------------- CSR build ----------------

__global__ void hist_kernel(const int* __restrict__ ei, int* __restrict__ deg_dst,
                            int* __restrict__ deg_src) {
    int e = blockIdx.x * blockDim.x + threadIdx.x;
    if (e >= NEDGES) return;
    int s = ei[e];
    int d = ei[NEDGES + e];
    atomicAdd(&deg_dst[d], 1);
    atomicAdd(&deg_src[s], 1);
}

// inclusive scan within 1024-chunks; rp[gid+1] = chunk-local inclusive; bsum = chunk total
__global__ void scan1_kernel(const int* __restrict__ deg_dst, const int* __restrict__ deg_src,
                             int* __restrict__ rp_dst, int* __restrict__ rp_src,
                             int* __restrict__ bsum) {
    __shared__ int sh[SCAN_CHUNK];
    const int* deg = (blockIdx.y == 0) ? deg_dst : deg_src;
    int* rp = (blockIdx.y == 0) ? rp_dst : rp_src;
    int t = threadIdx.x;
    int gid = blockIdx.x * SCAN_CHUNK + t;
    int v = (gid < NNODES) ? deg[gid] : 0;
    sh[t] = v;
    __syncthreads();
    for (int off = 1; off < SCAN_CHUNK; off <<= 1) {
        int u = (t >= off) ? sh[t - off] : 0;
        __syncthreads();
        sh[t] += u;
        __syncthreads();
    }
    if (gid < NNODES) rp[gid + 1] = sh[t];
    if (t == SCAN_CHUNK - 1) bsum[blockIdx.y * 64 + blockIdx.x] = sh[t];
}

__global__ void scan2_kernel(int* __restrict__ bsum) {
    int t = threadIdx.x;
    if (t < 2) {
        int run = 0;
        for (int i = 0; i < NCHUNK; i++) {
            int v = bsum[t * 64 + i];
            bsum[t * 64 + i] = run;
            run += v;
        }
    }
}

__global__ void scan3_kernel(int* __restrict__ rp_dst, int* __restrict__ rp_src,
                             const int* __restrict__ bsum) {
    int* rp = (blockIdx.y == 0) ? rp_dst : rp_src;
    int t = threadIdx.x;
    int gid = blockIdx.x * SCAN_CHUNK + t;
    int base = bsum[blockIdx.y * 64 + blockIdx.x];
    if (gid < NNODES) rp[gid + 1] += base;
    if (gid == 0) rp[0] = 0;
}

__global__ void fill_kernel(const int* __restrict__ ei, int* __restrict__ cur_dst,
                            int* __restrict__ cur_src, int* __restrict__ col_dst,
                            int* __restrict__ col_src) {
    int e = blockIdx.x * blockDim.x + threadIdx.x;
    if (e >= NEDGES) return;
    int s = ei[e];
    int d = ei[NEDGES + e];
    int p0 = atomicAdd(&cur_dst[d], 1);
    col_dst[p0] = s;
    int p1 = atomicAdd(&cur_src[s], 1);
    col_src[p1] = d;
}

// ---------------- GEMM (fp32, tiled) ----------------
// C[M,256] = A[M,256] @ W[256,256] + b
#define BM 64
#define BN 64
#define BK 16

__launch_bounds__(256)
__global__ void gemm_fp32(const float* __restrict__ A, const float* __restrict__ W,
                          const float* __restrict__ bvec, float* __restrict__ Cmat, int M) {
    __shared__ float As[BK][BM + 4];
    __shared__ float Bs[BK][BN + 4];
    int tx = threadIdx.x % 16, ty = threadIdx.x / 16;
    int m0 = blockIdx.y * BM, n0 = blockIdx.x * BN;
    float acc[4][4] = {};
    for (int k0 = 0; k0 < DIM; k0 += BK) {
        {
            int t = threadIdx.x;
            int row = t >> 2;            // 0..63
            int kk = (t & 3) << 2;       // 0,4,8,12
            int gr = m0 + row;
            float4 v = make_float4(0.f, 0.f, 0.f, 0.f);
            if (gr < M) v = *(const float4*)(A + (size_t)gr * DIM + k0 + kk);
            As[kk + 0][row] = v.x;
            As[kk + 1][row] = v.y;
            As[kk + 2][row] = v.z;
            As[kk + 3][row] = v.w;
        }
        {
            int t = threadIdx.x;
            int k = t >> 4;              // 0..15
            int cc = (t & 15) << 2;      // 0..60
            float4 v = *(const float4*)(W + (size_t)(k0 + k) * HC + n0 + cc);
            Bs[k][cc + 0] = v.x;
            Bs[k][cc + 1] = v.y;
            Bs[k][cc + 2] = v.z;
            Bs[k][cc + 3] = v.w;
        }
        __syncthreads();
#pragma unroll
        for (int k = 0; k < BK; k++) {
            float a[4], b[4];
#pragma unroll
            for (int i = 0; i < 4; i++) a[i] = As[k][ty * 4 + i];
#pragma unroll
            for (int j = 0; j < 4; j++) b[j] = Bs[k][tx * 4 + j];
#pragma unroll
            for (int i = 0; i < 4; i++)
#pragma unroll
                for (int j = 0; j < 4; j++) acc[i][j] += a[i] * b[j];
        }
        __syncthreads();
    }
#pragma unroll
    for (int i = 0; i < 4; i++) {
        int gr = m0 + ty * 4 + i;
        if (gr >= M) continue;
#pragma unroll
        for (int j = 0; j < 4; j++) {
            int gc = n0 + tx * 4 + j;
            Cmat[(size_t)gr * HC + gc] = acc[i][j] + bvec[gc];
        }
    }
}

// ---------------- fused attention + aggregate ----------------
// One 64-lane wave per destination node. lane l covers channels 4l..4l+3 (head = l>>3).
// out[n] = (sum_e exp(logit_e) * hl[nb_e]) / (sum_e exp(logit_e) + 1e-16) + bias
__launch_bounds__(256)
__global__ void agg_kernel(const float* __restrict__ hl, const float* __restrict__ hr,
                           const int* __restrict__ rowptr, const int* __restrict__ col,
                           const float* __restrict__ att, const float* __restrict__ bias,
                           float* __restrict__ out, int do_relu) {
    int wave = threadIdx.x >> 6;
    int lane = threadIdx.x & 63;
    int n = blockIdx.x * 4 + wave;
    if (n >= NNODES) return;

    int c4 = lane << 2;
    float4 hr4 = *(const float4*)(hr + (size_t)n * HC + c4);
    float4 att4 = *(const float4*)(att + c4);
    float4 b4 = *(const float4*)(bias + c4);

    float4 acc = make_float4(0.f, 0.f, 0.f, 0.f);
    float denom = 0.f;
    int beg = rowptr[n], end = rowptr[n + 1];
    for (int i = beg; i < end; i++) {
        int s = col[i];
        float4 h4 = *(const float4*)(hl + (size_t)s * HC + c4);
        float4 x4 = make_float4(h4.x + hr4.x, h4.y + hr4.y, h4.z + hr4.z, h4.w + hr4.w);
        float4 e4;
        e4.x = x4.x > 0.f ? x4.x : NEG_SLOPE * x4.x;
        e4.y = x4.y > 0.f ? x4.y : NEG_SLOPE * x4.y;
        e4.z = x4.z > 0.f ? x4.z : NEG_SLOPE * x4.z;
        e4.w = x4.w > 0.f ? x4.w : NEG_SLOPE * x4.w;
        float v = att4.x * e4.x + att4.y * e4.y + att4.z * e4.z + att4.w * e4.w;
        // reduce over 8-lane group (one head = 8 lanes * 4 channels)
        v += __shfl_xor(v, 1);
        v += __shfl_xor(v, 2);
        v += __shfl_xor(v, 4);
        float p = __expf(v);
        denom += p;
        acc.x += p * h4.x;
        acc.y += p * h4.y;
        acc.z += p * h4.z;
        acc.w += p * h4.w;
    }
    float inv = 1.f / (denom + 1e-16f);
    float4 o;
    o.x = acc.x * inv + b4.x;
    o.y = acc.y * inv + b4.y;
    o.z = acc.z * inv + b4.z;
    o.w = acc.w * inv + b4.w;
    if (do_relu) {
        o.x = fmaxf(o.x, 0.f);
        o.y = fmaxf(o.y, 0.f);
        o.z = fmaxf(o.z, 0.f);
        o.w = fmaxf(o.w, 0.f);
    }
    *(float4*)(out + (size_t)n * HC + c4) = o;
}

// ---------------- launch ----------------

extern "C" void kernel_launch(void* const* d_in, const int* in_sizes, int n_in,
                              void* d_out, int out_size, void* d_ws, size_t ws_size,
                              hipStream_t stream) {
    const float* s = (const float*)d_in[0];
    const float* t = (const float*)d_in[1];
    const float* Wl = (const float*)d_in[2];
    const float* bl = (const float*)d_in[3];
    const float* Wr = (const float*)d_in[4];
    const float* br = (const float*)d_in[5];
    const float* att = (const float*)d_in[6];
    const float* bias = (const float*)d_in[7];
    const int* ei = (const int*)d_in[8];
    float* out = (float*)d_out;

    // workspace layout
    float* ws = (float*)d_ws;
    float* xs1 = ws;                          // N*256
    float* xt1 = xs1 + (size_t)NNODES * HC;   // N*256
    float* hl = xt1 + (size_t)NNODES * HC;    // N*256
    float* hr = hl + (size_t)NNODES * HC;     // N*256
    int* deg_dst = (int*)(hr + (size_t)NNODES * HC);  // N
    int* deg_src = deg_dst + NNODES;                  // N
    int* rp_dst = deg_src + NNODES;                   // N+1
    int* rp_src = rp_dst + (NNODES + 1);              // N+1
    int* cur_dst = rp_src + (NNODES + 1);             // N
    int* cur_src = cur_dst + NNODES;                  // N
    int* bsum = cur_src + NNODES;                     // 128
    int* col_dst = bsum + 128;                        // E
    int* col_src = col_dst + NEDGES;                  // E

    // ---- CSR build ----
    hipMemsetAsync(deg_dst, 0, 2 * NNODES * sizeof(int), stream);
    hist_kernel<<<(NEDGES + 255) / 256, 256, 0, stream>>>(ei, deg_dst, deg_src);
    {
        dim3 g(NCHUNK, 2);
        scan1_kernel<<<g, SCAN_CHUNK, 0, stream>>>(deg_dst, deg_src, rp_dst, rp_src, bsum);
        scan2_kernel<<<1, 64, 0, stream>>>(bsum);
        scan3_kernel<<<g, SCAN_CHUNK, 0, stream>>>(rp_dst, rp_src, bsum);
    }
    hipMemcpyAsync(cur_dst, rp_dst, NNODES * sizeof(int), hipMemcpyDeviceToDevice, stream);
    hipMemcpyAsync(cur_src, rp_src, NNODES * sizeof(int), hipMemcpyDeviceToDevice, stream);
    fill_kernel<<<(NEDGES + 255) / 256, 256, 0, stream>>>(ei, cur_dst, cur_src, col_dst, col_src);

    dim3 ggemm(HC / BN, (NNODES + BM - 1) / BM);
    int gagg = (NNODES + 3) / 4;

    const float* xs = s;
    const float* xt = t;
    float* os = xs1;
    float* ot = xt1;
    for (int l = 0; l < 2; l++) {
        int enc0 = 2 * l, enc1 = 2 * l + 1;
        int do_relu = (l == 0) ? 1 : 0;
        if (l == 1) { os = out; ot = out + (size_t)NNODES * HC; }
        // source encoder: hl = xs @ Wl[enc0], hr = xt @ Wr[enc0], aggregate by dst
        gemm_fp32<<<ggemm, 256, 0, stream>>>(xs, Wl + (size_t)enc0 * DIM * HC, bl + (size_t)enc0 * HC, hl, NNODES);
        gemm_fp32<<<ggemm, 256, 0, stream>>>(xt, Wr + (size_t)enc0 * DIM * HC, br + (size_t)enc0 * HC, hr, NNODES);
        agg_kernel<<<gagg, 256, 0, stream>>>(hl, hr, rp_dst, col_dst, att + (size_t)enc0 * HC,
                                             bias + (size_t)enc0 * HC, os, do_relu);
        // target encoder (flipped edges): hl = xt @ Wl[enc1], hr = xs @ Wr[enc1], aggregate by src
        gemm_fp32<<<ggemm, 256, 0, stream>>>(xt, Wl + (size_t)enc1 * DIM * HC, bl + (size_t)enc1 * HC, hl, NNODES);
        gemm_fp32<<<ggemm, 256, 0, stream>>>(xs, Wr + (size_t)enc1 * DIM * HC, br + (size_t)enc1 * HC, hr, NNODES);
        agg_kernel<<<gagg, 256, 0, stream>>>(hl, hr, rp_src, col_src, att + (size_t)enc1 * HC,
                                             bias + (size_t)enc1 * HC, ot, do_relu);
        xs = os;
        xt = ot;
        os = xs1;
        ot = xt1;
    }
}

// Round 2
// 455.925 us; speedup vs baseline: 1.9955x; 1.9955x over previous
//
#include <hip/hip_runtime.h>
#include <hip/hip_bf16.h>

#define NNODES 30000
#define NEDGES 480000
#define DIM 256
#define HC 256
#define NEG_SLOPE 0.2f
#define SCAN_CHUNK 1024
#define NCHUNK 30   // ceil(30000/1024)

typedef _Float16 half8 __attribute__((ext_vector_type(8)));
typedef _Float16 half4v __attribute__((ext_vector_type(4)));
typedef float floatx4 __attribute__((ext_vector_type(4)));

// ---------------- CSR build ----------------

__global__ void hist_kernel(const int* __restrict__ ei, int* __restrict__ deg_dst,
                            int* __restrict__ deg_src) {
    int e = blockIdx.x * blockDim.x + threadIdx.x;
    if (e >= NEDGES) return;
    int s = ei[e];
    int d = ei[NEDGES + e];
    atomicAdd(&deg_dst[d], 1);
    atomicAdd(&deg_src[s], 1);
}

__global__ void scan1_kernel(const int* __restrict__ deg_dst, const int* __restrict__ deg_src,
                             int* __restrict__ rp_dst, int* __restrict__ rp_src,
                             int* __restrict__ bsum) {
    __shared__ int sh[SCAN_CHUNK];
    const int* deg = (blockIdx.y == 0) ? deg_dst : deg_src;
    int* rp = (blockIdx.y == 0) ? rp_dst : rp_src;
    int t = threadIdx.x;
    int gid = blockIdx.x * SCAN_CHUNK + t;
    int v = (gid < NNODES) ? deg[gid] : 0;
    sh[t] = v;
    __syncthreads();
    for (int off = 1; off < SCAN_CHUNK; off <<= 1) {
        int u = (t >= off) ? sh[t - off] : 0;
        __syncthreads();
        sh[t] += u;
        __syncthreads();
    }
    if (gid < NNODES) rp[gid + 1] = sh[t];
    if (t == SCAN_CHUNK - 1) bsum[blockIdx.y * 64 + blockIdx.x] = sh[t];
}

__global__ void scan2_kernel(int* __restrict__ bsum) {
    int t = threadIdx.x;
    if (t < 2) {
        int run = 0;
        for (int i = 0; i < NCHUNK; i++) {
            int v = bsum[t * 64 + i];
            bsum[t * 64 + i] = run;
            run += v;
        }
    }
}

__global__ void scan3_kernel(int* __restrict__ rp_dst, int* __restrict__ rp_src,
                             const int* __restrict__ bsum) {
    int* rp = (blockIdx.y == 0) ? rp_dst : rp_src;
    int t = threadIdx.x;
    int gid = blockIdx.x * SCAN_CHUNK + t;
    int base = bsum[blockIdx.y * 64 + blockIdx.x];
    if (gid < NNODES) rp[gid + 1] += base;
    if (gid == 0) rp[0] = 0;
}

__global__ void fill_kernel(const int* __restrict__ ei, int* __restrict__ cur_dst,
                            int* __restrict__ cur_src, int* __restrict__ col_dst,
                            int* __restrict__ col_src) {
    int e = blockIdx.x * blockDim.x + threadIdx.x;
    if (e >= NEDGES) return;
    int s = ei[e];
    int d = ei[NEDGES + e];
    int p0 = atomicAdd(&cur_dst[d], 1);
    col_dst[p0] = s;
    int p1 = atomicAdd(&cur_src[s], 1);
    col_src[p1] = d;
}

// ---------------- conversions ----------------

// y==0: s -> out0 ; y==1: t -> out1   (vec4)
__global__ void cvt_f16(const float* __restrict__ in0, _Float16* __restrict__ out0,
                        const float* __restrict__ in1, _Float16* __restrict__ out1) {
    const float* in = blockIdx.y ? in1 : in0;
    _Float16* out = blockIdx.y ? out1 : out0;
    int i = blockIdx.x * blockDim.x + threadIdx.x;
    float4 v = ((const float4*)in)[i];
    half4v h = {(_Float16)v.x, (_Float16)v.y, (_Float16)v.z, (_Float16)v.w};
    ((half4v*)out)[i] = h;
}

// transpose + convert weights: Wt[n][k] = W[k][n], fp16
__global__ void wtrans_kernel(const float* __restrict__ Wl, const float* __restrict__ Wr,
                              _Float16* __restrict__ WtL, _Float16* __restrict__ WtR) {
    __shared__ float sh[32][33];
    int e = blockIdx.z;
    const float* W = (e < 4) ? Wl + (size_t)e * 65536 : Wr + (size_t)(e - 4) * 65536;
    _Float16* Wt = (e < 4) ? WtL + (size_t)e * 65536 : WtR + (size_t)(e - 4) * 65536;
    int r0 = blockIdx.y * 32, c0 = blockIdx.x * 32;
    int x = threadIdx.x, y = threadIdx.y;  // 32 x 8
#pragma unroll
    for (int j = 0; j < 4; j++) {
        int r = y + j * 8;
        sh[r][x] = W[(size_t)(r0 + r) * 256 + c0 + x];
    }
    __syncthreads();
#pragma unroll
    for (int j = 0; j < 4; j++) {
        int nn = y + j * 8;
        Wt[(size_t)(c0 + nn) * 256 + r0 + x] = (_Float16)sh[x][nn];
    }
}

// ---------------- fp16 MFMA GEMM ----------------
// C[M,256] = A[M,256] @ W[256,256] + b   (W given transposed: Wt[n][k])
// Block: 256 thr (4 waves), tile BM=64 x N=256. Wave w -> cols [w*64, w*64+64).
// grid.y in {0,1} selects the (A,Wt,b,C) set -> fuses hl & hr GEMMs in one launch.
__launch_bounds__(256)
__global__ void gemm_f16(const _Float16* __restrict__ A0, const _Float16* __restrict__ Wt0,
                         const float* __restrict__ b0, _Float16* __restrict__ C0,
                         const _Float16* __restrict__ A1, const _Float16* __restrict__ Wt1,
                         const float* __restrict__ b1, _Float16* __restrict__ C1) {
    const _Float16* A = blockIdx.y ? A1 : A0;
    const _Float16* Wt = blockIdx.y ? Wt1 : Wt0;
    const float* bvec = blockIdx.y ? b1 : b0;
    _Float16* C = blockIdx.y ? C1 : C0;

    // swizzled LDS: row stride 32 halfs (64B), chunk slot = c ^ ((row>>1)&3)
    __shared__ __align__(16) _Float16 As[64 * 32];
    __shared__ __align__(16) _Float16 Bs[256 * 32];

    const int t = threadIdx.x;
    const int lane = t & 63, w = t >> 6;
    const int m0 = blockIdx.x * 64;
    const int rl = lane & 15, ch = lane >> 4;

    // staging map: A chunk per thread: row=t>>2, chunk=t&3 ; B: 4 chunks, rows t>>2 + j*64
    const int ar = t >> 2, ac = t & 3;

    floatx4 acc[4][4] = {};

    for (int k0 = 0; k0 < 256; k0 += 32) {
        half8 av = {};
        {
            int gr = m0 + ar;
            if (gr < NNODES) av = *(const half8*)(A + (size_t)gr * 256 + k0 + ac * 8);
        }
        half8 bv[4];
#pragma unroll
        for (int j = 0; j < 4; j++) {
            int n = ar + j * 64;
            bv[j] = *(const half8*)(Wt + (size_t)n * 256 + k0 + ac * 8);
        }
        __syncthreads();  // previous iteration's readers done
        *(half8*)(As + ar * 32 + (ac ^ ((ar >> 1) & 3)) * 8) = av;
#pragma unroll
        for (int j = 0; j < 4; j++) {
            int n = ar + j * 64;
            *(half8*)(Bs + n * 32 + (ac ^ ((n >> 1) & 3)) * 8) = bv[j];
        }
        __syncthreads();

        half8 a[4], b[4];
#pragma unroll
        for (int fm = 0; fm < 4; fm++) {
            int r = fm * 16 + rl;
            a[fm] = *(const half8*)(As + r * 32 + (ch ^ ((r >> 1) & 3)) * 8);
        }
#pragma unroll
        for (int fn = 0; fn < 4; fn++) {
            int n = w * 64 + fn * 16 + rl;
            b[fn] = *(const half8*)(Bs + n * 32 + (ch ^ ((n >> 1) & 3)) * 8);
        }
#pragma unroll
        for (int fm = 0; fm < 4; fm++)
#pragma unroll
            for (int fn = 0; fn < 4; fn++)
                acc[fm][fn] = __builtin_amdgcn_mfma_f32_16x16x32_f16(a[fm], b[fn], acc[fm][fn], 0, 0, 0);
    }

    // epilogue: D row = (lane>>4)*4 + j, col = lane&15 within frag
#pragma unroll
    for (int fn = 0; fn < 4; fn++) {
        int colb = w * 64 + fn * 16 + rl;
        float bb = bvec[colb];
#pragma unroll
        for (int fm = 0; fm < 4; fm++) {
#pragma unroll
            for (int j = 0; j < 4; j++) {
                int row = m0 + fm * 16 + ch * 4 + j;
                if (row < NNODES) C[(size_t)row * 256 + colb] = (_Float16)(acc[fm][fn][j] + bb);
            }
        }
    }
}

// ---------------- fused attention + aggregate ----------------

__device__ inline float4 ld4h(const _Float16* p) {
    half4v v = *(const half4v*)p;
    return make_float4((float)v[0], (float)v[1], (float)v[2], (float)v[3]);
}
__device__ inline void store4(float* p, float4 v) { *(float4*)p = v; }
__device__ inline void store4(_Float16* p, float4 v) {
    half4v h = {(_Float16)v.x, (_Float16)v.y, (_Float16)v.z, (_Float16)v.w};
    *(half4v*)p = h;
}

template <typename OT>
__launch_bounds__(256)
__global__ void agg_kernel(const _Float16* __restrict__ hl, const _Float16* __restrict__ hr,
                           const int* __restrict__ rowptr, const int* __restrict__ col,
                           const float* __restrict__ att, const float* __restrict__ bias,
                           OT* __restrict__ out, int do_relu) {
    int wave = threadIdx.x >> 6;
    int lane = threadIdx.x & 63;
    int n = blockIdx.x * 4 + wave;
    if (n >= NNODES) return;

    int c4 = lane << 2;
    float4 hr4 = ld4h(hr + (size_t)n * HC + c4);
    float4 att4 = *(const float4*)(att + c4);
    float4 b4 = *(const float4*)(bias + c4);

    float4 acc = make_float4(0.f, 0.f, 0.f, 0.f);
    float denom = 0.f;
    int beg = rowptr[n], end = rowptr[n + 1];

#define EDGE(h4)                                                                  \
    {                                                                             \
        float4 x4 = make_float4(h4.x + hr4.x, h4.y + hr4.y, h4.z + hr4.z, h4.w + hr4.w); \
        float4 e4;                                                                \
        e4.x = x4.x > 0.f ? x4.x : NEG_SLOPE * x4.x;                              \
        e4.y = x4.y > 0.f ? x4.y : NEG_SLOPE * x4.y;                              \
        e4.z = x4.z > 0.f ? x4.z : NEG_SLOPE * x4.z;                              \
        e4.w = x4.w > 0.f ? x4.w : NEG_SLOPE * x4.w;                              \
        float v = att4.x * e4.x + att4.y * e4.y + att4.z * e4.z + att4.w * e4.w;  \
        v += __shfl_xor(v, 1);                                                    \
        v += __shfl_xor(v, 2);                                                    \
        v += __shfl_xor(v, 4);                                                    \
        float p = __expf(v);                                                      \
        denom += p;                                                               \
        acc.x += p * h4.x;                                                        \
        acc.y += p * h4.y;                                                        \
        acc.z += p * h4.z;                                                        \
        acc.w += p * h4.w;                                                        \
    }

    int i = beg;
    for (; i + 2 <= end; i += 2) {
        int s0 = col[i], s1 = col[i + 1];
        float4 h0 = ld4h(hl + (size_t)s0 * HC + c4);
        float4 h1 = ld4h(hl + (size_t)s1 * HC + c4);
        EDGE(h0);
        EDGE(h1);
    }
    if (i < end) {
        int s0 = col[i];
        float4 h0 = ld4h(hl + (size_t)s0 * HC + c4);
        EDGE(h0);
    }
#undef EDGE

    float inv = 1.f / (denom + 1e-16f);
    float4 o;
    o.x = acc.x * inv + b4.x;
    o.y = acc.y * inv + b4.y;
    o.z = acc.z * inv + b4.z;
    o.w = acc.w * inv + b4.w;
    if (do_relu) {
        o.x = fmaxf(o.x, 0.f);
        o.y = fmaxf(o.y, 0.f);
        o.z = fmaxf(o.z, 0.f);
        o.w = fmaxf(o.w, 0.f);
    }
    store4(out + (size_t)n * HC + c4, o);
}

// ---------------- launch ----------------

extern "C" void kernel_launch(void* const* d_in, const int* in_sizes, int n_in,
                              void* d_out, int out_size, void* d_ws, size_t ws_size,
                              hipStream_t stream) {
    const float* s = (const float*)d_in[0];
    const float* t = (const float*)d_in[1];
    const float* Wl = (const float*)d_in[2];
    const float* bl = (const float*)d_in[3];
    const float* Wr = (const float*)d_in[4];
    const float* br = (const float*)d_in[5];
    const float* att = (const float*)d_in[6];
    const float* bias = (const float*)d_in[7];
    const int* ei = (const int*)d_in[8];
    float* out = (float*)d_out;

    const size_t NF = (size_t)NNODES * HC;  // 7.68M elems

    // workspace layout (halfs first, then ints)
    _Float16* xs16 = (_Float16*)d_ws;
    _Float16* xt16 = xs16 + NF;
    _Float16* os16 = xt16 + NF;
    _Float16* ot16 = os16 + NF;
    _Float16* hl16 = ot16 + NF;
    _Float16* hr16 = hl16 + NF;
    _Float16* WtL = hr16 + NF;            // 4*65536
    _Float16* WtR = WtL + 4 * 65536;      // 4*65536
    int* deg_dst = (int*)(WtR + 4 * 65536);
    int* deg_src = deg_dst + NNODES;
    int* rp_dst = deg_src + NNODES;
    int* rp_src = rp_dst + (NNODES + 1);
    int* cur_dst = rp_src + (NNODES + 1);
    int* cur_src = cur_dst + NNODES;
    int* bsum = cur_src + NNODES;
    int* col_dst = bsum + 128;
    int* col_src = col_dst + NEDGES;

    // ---- conversions ----
    {
        dim3 g(NF / 4 / 256, 2);
        cvt_f16<<<g, 256, 0, stream>>>(s, xs16, t, xt16);
        dim3 gw(8, 8, 8);
        wtrans_kernel<<<gw, dim3(32, 8), 0, stream>>>(Wl, Wr, WtL, WtR);
    }

    // ---- CSR build ----
    hipMemsetAsync(deg_dst, 0, 2 * NNODES * sizeof(int), stream);
    hist_kernel<<<(NEDGES + 255) / 256, 256, 0, stream>>>(ei, deg_dst, deg_src);
    {
        dim3 g(NCHUNK, 2);
        scan1_kernel<<<g, SCAN_CHUNK, 0, stream>>>(deg_dst, deg_src, rp_dst, rp_src, bsum);
        scan2_kernel<<<1, 64, 0, stream>>>(bsum);
        scan3_kernel<<<g, SCAN_CHUNK, 0, stream>>>(rp_dst, rp_src, bsum);
    }
    hipMemcpyAsync(cur_dst, rp_dst, NNODES * sizeof(int), hipMemcpyDeviceToDevice, stream);
    hipMemcpyAsync(cur_src, rp_src, NNODES * sizeof(int), hipMemcpyDeviceToDevice, stream);
    fill_kernel<<<(NEDGES + 255) / 256, 256, 0, stream>>>(ei, cur_dst, cur_src, col_dst, col_src);

    dim3 ggemm((NNODES + 63) / 64, 2);
    int gagg = (NNODES + 3) / 4;

    const _Float16* xs = xs16;
    const _Float16* xt = xt16;
    for (int l = 0; l < 2; l++) {
        int e0 = 2 * l, e1 = 2 * l + 1;
        int do_relu = (l == 0) ? 1 : 0;
        // source encoder: hl = xs @ Wl[e0], hr = xt @ Wr[e0], aggregate by dst
        gemm_f16<<<ggemm, 256, 0, stream>>>(xs, WtL + (size_t)e0 * 65536, bl + (size_t)e0 * HC, hl16,
                                            xt, WtR + (size_t)e0 * 65536, br + (size_t)e0 * HC, hr16);
        if (l == 0)
            agg_kernel<_Float16><<<gagg, 256, 0, stream>>>(hl16, hr16, rp_dst, col_dst,
                                                           att + (size_t)e0 * HC, bias + (size_t)e0 * HC,
                                                           os16, do_relu);
        else
            agg_kernel<float><<<gagg, 256, 0, stream>>>(hl16, hr16, rp_dst, col_dst,
                                                        att + (size_t)e0 * HC, bias + (size_t)e0 * HC,
                                                        out, do_relu);
        // target encoder (flipped edges): hl = xt @ Wl[e1], hr = xs @ Wr[e1], aggregate by src
        gemm_f16<<<ggemm, 256, 0, stream>>>(xt, WtL + (size_t)e1 * 65536, bl + (size_t)e1 * HC, hl16,
                                            xs, WtR + (size_t)e1 * 65536, br + (size_t)e1 * HC, hr16);
        if (l == 0)
            agg_kernel<_Float16><<<gagg, 256, 0, stream>>>(hl16, hr16, rp_src, col_src,
                                                           att + (size_t)e1 * HC, bias + (size_t)e1 * HC,
                                                           ot16, do_relu);
        else
            agg_kernel<float><<<gagg, 256, 0, stream>>>(hl16, hr16, rp_src, col_src,
                                                        att + (size_t)e1 * HC, bias + (size_t)e1 * HC,
                                                        out + NF, do_relu);
        xs = os16;
        xt = ot16;
    }
}